// Round 13
// baseline (218.848 us; speedup 1.0000x reference)
//
#include <hip/hip_runtime.h>
#include <math.h>

#define BB 4
#define LL 4096
#define CC 768
#define KHH 7
#define PADK 3
#define ROWS (BB*LL)      // 16384
#define NKP  (BB*KHH*LL)  // 114688
#define GK   (KHH*CC)     // 5376
#define NT   (GK/64)      // 84
#define NKB  (GK/16)      // 336 k-slices of 16

typedef unsigned short ushort8 __attribute__((ext_vector_type(8)));
typedef short short8 __attribute__((ext_vector_type(8)));
typedef float f32x4 __attribute__((ext_vector_type(4)));
typedef float f32x16 __attribute__((ext_vector_type(16)));

__device__ __forceinline__ float bf2f(unsigned short u) {
    return __uint_as_float(((unsigned)u) << 16);
}
__device__ __forceinline__ unsigned short f2bf(float x) {
    unsigned u = __float_as_uint(x);
    return (unsigned short)((u + 0x7FFFu + ((u >> 16) & 1u)) >> 16);
}

// ---------------- K1: layernorm + gate -> h_bf16 ----------------
__global__ __launch_bounds__(256) void k_ln(const float* __restrict__ x,
        const float* __restrict__ mask, const float* __restrict__ special,
        const float* __restrict__ lnw, const float* __restrict__ lnb,
        unsigned short* __restrict__ hb, float* __restrict__ gate) {
    int row = blockIdx.x;
    const float* xr = x + (size_t)row * CC;
    float s = 0.f, q = 0.f;
    for (int i = threadIdx.x; i < CC; i += 256) { float v = xr[i]; s += v; q += v * v; }
    for (int o = 32; o; o >>= 1) { s += __shfl_xor(s, o); q += __shfl_xor(q, o); }
    __shared__ float ss[4], sq[4];
    int wid = threadIdx.x >> 6;
    if ((threadIdx.x & 63) == 0) { ss[wid] = s; sq[wid] = q; }
    __syncthreads();
    s = ss[0] + ss[1] + ss[2] + ss[3];
    q = sq[0] + sq[1] + sq[2] + sq[3];
    float mu  = s * (1.f / CC);
    float var = fmaxf(q * (1.f / CC) - mu * mu, 0.f);
    float rstd = rsqrtf(var + 1e-12f);
    unsigned short* hr = hb + (size_t)row * CC;
    for (int i = threadIdx.x; i < CC; i += 256)
        hr[i] = f2bf((xr[i] - mu) * rstd * lnw[i] + lnb[i]);
    if (threadIdx.x == 0) gate[row] = (1.f - special[row]) * mask[row];
}

// ---------------- K2: reg_w[o][c][k] -> Wbt2 fragment-native for 32x32x16 ----------------
// frag (kb = K/16, c32 = o/32) is 1024 B: lane = (o&31) + 32*((kk>>3)&1), elem = kk&7
__global__ __launch_bounds__(256) void k_wbt(const float* __restrict__ rw,
                                             unsigned short* __restrict__ wbt) {
    __shared__ float s[GK];
    int o = blockIdx.x;
    for (int i = threadIdx.x; i < GK; i += 256) s[i] = rw[(size_t)o * GK + i];
    __syncthreads();
    for (int kk = threadIdx.x; kk < GK; kk += 256) {
        int k = kk / CC, c = kk - k * CC;     // kk = k*768 + c
        float v = s[c * KHH + k];
        size_t off = (size_t)((kk >> 4) * 24 + (o >> 5)) * 512
                   + (size_t)((kk >> 3) & 1) * 256
                   + (size_t)(o & 31) * 8 + (kk & 7);
        wbt[off] = f2bf(v);
    }
}

// ---------------- K2b: conv weights -> wcb[i][c] bf16 ----------------
__global__ __launch_bounds__(256) void k_wcb(const float* __restrict__ ow, const float* __restrict__ mw,
                                             unsigned short* __restrict__ wcb) {
    int i = blockIdx.x;
    for (int c = threadIdx.x; c < CC; c += 256) {
        float v = 0.f;
        if (i < 49)      v = ow[(size_t)(i / 7) * (CC * KHH) + (size_t)c * KHH + (i % 7)];
        else if (i < 98) { int j = i - 49; v = mw[(size_t)(j / 7) * (CC * KHH) + (size_t)c * KHH + (j % 7)]; }
        wcb[(size_t)i * CC + c] = f2bf(v);
    }
}

// ---------------- K3: d[row][i] = sum_c hb[row][c] * wcb[i][c] ----------------
__global__ __launch_bounds__(256) void k_dg2(const unsigned short* __restrict__ A,
        const unsigned short* __restrict__ Bm, float* __restrict__ d) {
    __shared__ __align__(16) char As[128 * 128];
    __shared__ __align__(16) char Bs[128 * 128];
    int r0 = blockIdx.x * 128;
    int t = threadIdx.x;
    int lane = t & 63, w = t >> 6;
    int wr = w >> 1, wc = w & 1;
    f32x4 acc[4][4];
#pragma unroll
    for (int m = 0; m < 4; ++m)
#pragma unroll
        for (int n = 0; n < 4; ++n) acc[m][n] = (f32x4){0.f, 0.f, 0.f, 0.f};
    int lr = lane & 15;
    int lkb0 = (lane >> 4) * 16;
    for (int kk = 0; kk < CC; kk += 64) {
#pragma unroll
        for (int s = 0; s < 4; ++s) {
            int byteoff = (s * 256 + t) * 16;
            int row = byteoff >> 7;
            int colb = byteoff & 127;
            int sw = (row * 128 + colb) ^ ((row & 7) << 4);
            *(ushort8*)(As + sw) = *(const ushort8*)(A + (size_t)(r0 + row) * CC + kk + (colb >> 1));
            *(ushort8*)(Bs + sw) = *(const ushort8*)(Bm + (size_t)row * CC + kk + (colb >> 1));
        }
        __syncthreads();
#pragma unroll
        for (int ks = 0; ks < 2; ++ks) {
            short8 av[4], bv[4];
            int lkb = lkb0 + ks * 64;
#pragma unroll
            for (int m = 0; m < 4; ++m) {
                int ar = wr * 64 + m * 16 + lr;
                av[m] = *(const short8*)(As + ((ar * 128 + lkb) ^ ((ar & 7) << 4)));
            }
#pragma unroll
            for (int n = 0; n < 4; ++n) {
                int br = wc * 64 + n * 16 + lr;
                bv[n] = *(const short8*)(Bs + ((br * 128 + lkb) ^ ((br & 7) << 4)));
            }
#pragma unroll
            for (int m = 0; m < 4; ++m)
#pragma unroll
                for (int n = 0; n < 4; ++n)
                    acc[m][n] = __builtin_amdgcn_mfma_f32_16x16x32_bf16(av[m], bv[n], acc[m][n], 0, 0, 0);
        }
        __syncthreads();
    }
    int lr4 = (lane >> 4) * 4, lc = lane & 15;
#pragma unroll
    for (int m = 0; m < 4; ++m) {
        int gr = r0 + wr * 64 + m * 16 + lr4;
#pragma unroll
        for (int n = 0; n < 4; ++n) {
            int gc = wc * 64 + n * 16 + lc;
#pragma unroll
            for (int j = 0; j < 4; ++j)
                d[(size_t)(gr + j) * 128 + gc] = acc[m][n][j];
        }
    }
}

// ---------------- K4: sampling params ----------------
__global__ __launch_bounds__(256) void k_off(const float* __restrict__ d,
        const float* __restrict__ offb, const float* __restrict__ modb,
        const float* __restrict__ gate,
        int* __restrict__ idx0, int* __restrict__ idx1,
        float* __restrict__ w0a, float* __restrict__ w1a) {
    int flat = blockIdx.x * 256 + threadIdx.x;   // b*7*L + k*L + p
    if (flat >= NKP) return;
    int p = flat & (LL - 1);
    int k = (flat >> 12) % KHH;
    int b = flat / (KHH * LL);
    float offa = offb[k], moda = modb[k];
#pragma unroll
    for (int j = 0; j < KHH; ++j) {
        int q = p + j - PADK;
        if (q >= 0 && q < LL) {
            const float* dr = d + (size_t)(b * LL + q) * 128;
            offa += dr[k * 7 + j];
            moda += dr[49 + k * 7 + j];
        }
    }
    float modv = 2.f / (1.f + expf(-moda));
    float pos = (float)(p - PADK + k) + offa;
    pos = fminf(fmaxf(pos, -1.0e9f), 1.0e9f);
    float f = floorf(pos);
    float tf = pos - f;
    int i0 = (int)f;
    int i1 = i0 + 1;
    float in0 = (i0 >= 0 && i0 < LL) ? 1.f : 0.f;
    float in1 = (i1 >= 0 && i1 < LL) ? 1.f : 0.f;
    int c0 = min(max(i0, 0), LL - 1);
    int c1 = min(max(i1, 0), LL - 1);
    float g0 = gate[b * LL + c0] * in0;
    float g1 = gate[b * LL + c1] * in1;
    w0a[flat] = modv * (1.f - tf) * g0;
    w1a[flat] = modv * tf * g1;
    idx0[flat] = c0;
    idx1[flat] = c1;
}

// ---------------- K5: fused sample+GEMM on 32x32x16 MFMA ----------------
// BM=64, BN=384; 256 threads = 4 waves, wave tile 64x96 = 2x3 tiles of 32x32; 4 kslices/step
// A via LDS (pitch 256B, row&15 XOR swizzle); B global->frag regs (Wbt2), P/Q kslice rotation

#define KBOFF 12288     // shorts per kb (24 frags x 512)
#define STEPOFF 49152   // 4 kb per step

#define LOADB32(Q, D0, D1, D2) do { \
    D0 = *(const short8*)(Q); \
    D1 = *(const short8*)((Q) + 512); \
    D2 = *(const short8*)((Q) + 1024); \
} while (0)

#define COMPUTE32(ASB, KS, B0, B1, B2) do { \
    __builtin_amdgcn_s_setprio(1); \
    int _cb = ((KS) * 32 + kl * 16) ^ ((rA & 15) << 4); \
    short8 _a0 = *(const short8*)((ASB) + rA * 256 + _cb); \
    short8 _a1 = *(const short8*)((ASB) + (32 + rA) * 256 + _cb); \
    acc[0][0] = __builtin_amdgcn_mfma_f32_32x32x16_bf16(_a0, B0, acc[0][0], 0, 0, 0); \
    acc[0][1] = __builtin_amdgcn_mfma_f32_32x32x16_bf16(_a0, B1, acc[0][1], 0, 0, 0); \
    acc[0][2] = __builtin_amdgcn_mfma_f32_32x32x16_bf16(_a0, B2, acc[0][2], 0, 0, 0); \
    acc[1][0] = __builtin_amdgcn_mfma_f32_32x32x16_bf16(_a1, B0, acc[1][0], 0, 0, 0); \
    acc[1][1] = __builtin_amdgcn_mfma_f32_32x32x16_bf16(_a1, B1, acc[1][1], 0, 0, 0); \
    acc[1][2] = __builtin_amdgcn_mfma_f32_32x32x16_bf16(_a1, B2, acc[1][2], 0, 0, 0); \
    __builtin_amdgcn_s_setprio(0); \
} while (0)

// counted barrier: LDS drained, global loads stay in flight
#define BAR() do { \
    asm volatile("s_waitcnt lgkmcnt(0)" ::: "memory"); \
    __builtin_amdgcn_s_barrier(); \
    __builtin_amdgcn_sched_barrier(0); \
} while (0)

#define SBAR() __builtin_amdgcn_sched_barrier(0)

__global__ __launch_bounds__(256, 2) void k_fgemm(const unsigned short* __restrict__ hb,
        const unsigned short* __restrict__ Wbt,
        const int* __restrict__ idx0, const int* __restrict__ idx1,
        const float* __restrict__ w0a, const float* __restrict__ w1a,
        const float* __restrict__ resid, float* __restrict__ out) {
    __shared__ __align__(16) char As[2][64 * 256];

    int bid = blockIdx.x;
    int nhalf = (bid & 7) >> 2;                 // XCDs 0-3 -> half 0, 4-7 -> half 1
    int rowtile = (bid >> 3) * 4 + (bid & 3);   // bijective 0..255
    int r0 = rowtile * 64;
    int o0 = nhalf * 384;
    int b = r0 >> 12;
    int p0 = r0 & (LL - 1);
    int pbase = ((b * KHH) << 12) + p0;
    const unsigned short* hbB = hb + (size_t)b * LL * CC;

    int t = threadIdx.x;
    int lane = t & 63, wc = t >> 6;             // wave 0..3 owns 96-col strip
    int rA = lane & 31;                         // A-row within 32-tile / B-col within 32-tile
    int kl = lane >> 5;                         // k-octet selector

    // per-lane B base pointer into Wbt2; advances STEPOFF per step
    const unsigned short* pB = Wbt + (size_t)(nhalf * 12 + wc * 3) * 512 + (size_t)lane * 8;

    // A-build mapping: row = t>>2 (0..63), seg = t&3 (16 elems each); pitch 256B
    int arow = t >> 2, aseg = t & 3;
    int aswz0 = arow * 256 + ((aseg * 32) ^ ((arow & 15) << 4));
    int aswz1 = arow * 256 + ((aseg * 32 + 16) ^ ((arow & 15) << 4));

    f32x16 acc[2][3];
#pragma unroll
    for (int m = 0; m < 2; ++m)
#pragma unroll
        for (int n = 0; n < 3; ++n)
#pragma unroll
            for (int e = 0; e < 16; ++e) acc[m][n][e] = 0.f;

    // per-tap sampling regs
    int g0 = 0, g1 = 0;
    float wa = 0.f, wbv = 0.f;
    int cur_tap = -1;

    // staging registers (individually named)
    ushort8 la0, la1, la2, la3;
    short8 P0, P1, P2;   // even kslices
    short8 Q0, Q1, Q2;   // odd kslices

    auto loadA = [&](int tap, int c0) {
        if (tap != cur_tap) {
            int pf = pbase + (tap << 12) + arow;
            g0 = idx0[pf]; g1 = idx1[pf];
            wa = w0a[pf];  wbv = w1a[pf];
            cur_tap = tap;
        }
        const unsigned short* s0 = hbB + (size_t)g0 * CC + c0 + aseg * 16;
        const unsigned short* s1 = hbB + (size_t)g1 * CC + c0 + aseg * 16;
        la0 = *(const ushort8*)(s0);
        la1 = *(const ushort8*)(s0 + 8);
        la2 = *(const ushort8*)(s1);
        la3 = *(const ushort8*)(s1 + 8);
    };

    auto writeA = [&](char* Asb) {
        ushort8 ra, rb;
#pragma unroll
        for (int e = 0; e < 8; ++e) ra[e] = f2bf(fmaf(wa, bf2f(la0[e]), wbv * bf2f(la2[e])));
#pragma unroll
        for (int e = 0; e < 8; ++e) rb[e] = f2bf(fmaf(wa, bf2f(la1[e]), wbv * bf2f(la3[e])));
        *(ushort8*)(Asb + aswz0) = ra;
        *(ushort8*)(Asb + aswz1) = rb;
    };

    // prologue: A(0) staged; B ks0 -> P
    loadA(0, 0);
    LOADB32(pB, P0, P1, P2);
    writeA(As[0]);
    BAR();

    int tap_c = 0, c0_c = 0;
    for (int s = 0; s < NT; ++s) {
        char* Asb = As[s & 1];
        char* Asn = As[(s & 1) ^ 1];
        int tap_n = tap_c, c0_n = c0_c + 64;
        if (c0_n == CC) { c0_n = 0; ++tap_n; }
        bool more = (s + 1 < NT);

        // ks0: issue A(s+1) gathers + B ks1 -> Q; compute P
        if (more) loadA(tap_n, c0_n);
        LOADB32(pB + KBOFF, Q0, Q1, Q2);
        SBAR();
        COMPUTE32(Asb, 0, P0, P1, P2);
        SBAR();
        // ks1: issue B ks2 -> P; compute Q
        LOADB32(pB + 2 * KBOFF, P0, P1, P2);
        SBAR();
        COMPUTE32(Asb, 1, Q0, Q1, Q2);
        SBAR();
        // ks2: issue B ks3 -> Q; compute P
        LOADB32(pB + 3 * KBOFF, Q0, Q1, Q2);
        SBAR();
        COMPUTE32(Asb, 2, P0, P1, P2);
        SBAR();
        // ks3: issue next-step ks0 -> P; compute Q
        if (more) LOADB32(pB + 4 * KBOFF, P0, P1, P2);
        SBAR();
        COMPUTE32(Asb, 3, Q0, Q1, Q2);
        SBAR();
        if (more) writeA(Asn);      // vmcnt wait on A gathers; lerp + ds_write
        BAR();
        pB += STEPOFF;
        tap_c = tap_n; c0_c = c0_n;
    }

    // epilogue: + residual (32x32 C layout: col=lane&31, row=(reg&3)+8*(reg>>2)+4*(lane>>5))
#pragma unroll
    for (int m = 0; m < 2; ++m) {
#pragma unroll
        for (int n = 0; n < 3; ++n) {
            int gc = o0 + wc * 96 + n * 32 + rA;
#pragma unroll
            for (int reg = 0; reg < 16; ++reg) {
                int r_in = (reg & 3) + 8 * (reg >> 2) + 4 * kl;
                size_t idx = (size_t)(r0 + m * 32 + r_in) * CC + gc;
                out[idx] = acc[m][n][reg] + resid[idx];
            }
        }
    }
}

extern "C" void kernel_launch(void* const* d_in, const int* in_sizes, int n_in,
                              void* d_out, int out_size, void* d_ws, size_t ws_size,
                              hipStream_t stream) {
    const float* x   = (const float*)d_in[0];
    const float* am  = (const float*)d_in[1];
    const float* stm = (const float*)d_in[2];
    const float* lnw = (const float*)d_in[3];
    const float* lnb = (const float*)d_in[4];
    const float* ow  = (const float*)d_in[5];
    const float* ob  = (const float*)d_in[6];
    const float* mw  = (const float*)d_in[7];
    const float* mb  = (const float*)d_in[8];
    const float* rw  = (const float*)d_in[9];
    float* out = (float*)d_out;

    char* ws = (char*)d_ws;
    size_t off = 0;
    auto carve = [&](size_t bytes) -> char* {
        char* p = ws + off;
        off += (bytes + 255) & ~(size_t)255;
        return p;
    };
    unsigned short* hb  = (unsigned short*)carve((size_t)ROWS * CC * 2);   // 25.2 MB
    unsigned short* wbt = (unsigned short*)carve((size_t)NKB * 24 * 512 * 2); // 8.25 MB
    unsigned short* wcb = (unsigned short*)carve((size_t)128 * CC * 2);    // 0.20 MB
    float* d    = (float*)carve((size_t)ROWS * 128 * 4);                   // 8.4 MB
    float* gate = (float*)carve((size_t)ROWS * 4);
    int*   i0   = (int*)carve((size_t)NKP * 4);
    int*   i1   = (int*)carve((size_t)NKP * 4);
    float* w0   = (float*)carve((size_t)NKP * 4);
    float* w1   = (float*)carve((size_t)NKP * 4);

    k_ln<<<ROWS, 256, 0, stream>>>(x, am, stm, lnw, lnb, hb, gate);
    k_wbt<<<CC, 256, 0, stream>>>(rw, wbt);
    k_wcb<<<128, 256, 0, stream>>>(ow, mw, wcb);
    k_dg2<<<ROWS / 128, 256, 0, stream>>>(hb, wcb, d);
    k_off<<<NKP / 256, 256, 0, stream>>>(d, ob, mb, gate, i0, i1, w0, w1);
    k_fgemm<<<512, 256, 0, stream>>>(hb, wbt, i0, i1, w0, w1, x, out);
}

// Round 14
// 215.773 us; speedup vs baseline: 1.0143x; 1.0143x over previous
//
#include <hip/hip_runtime.h>
#include <math.h>

#define BB 4
#define LL 4096
#define CC 768
#define KHH 7
#define PADK 3
#define ROWS (BB*LL)      // 16384
#define NKP  (BB*KHH*LL)  // 114688
#define GK   (KHH*CC)     // 5376
#define NT   (GK/64)      // 84
#define NKC  (GK/8)       // 672

typedef unsigned short ushort8 __attribute__((ext_vector_type(8)));
typedef short short8 __attribute__((ext_vector_type(8)));
typedef float f32x4 __attribute__((ext_vector_type(4)));

__device__ __forceinline__ float bf2f(unsigned short u) {
    return __uint_as_float(((unsigned)u) << 16);
}
__device__ __forceinline__ unsigned short f2bf(float x) {
    unsigned u = __float_as_uint(x);
    return (unsigned short)((u + 0x7FFFu + ((u >> 16) & 1u)) >> 16);
}

// ---------------- K1: layernorm + gate -> h_bf16 ----------------
__global__ __launch_bounds__(256) void k_ln(const float* __restrict__ x,
        const float* __restrict__ mask, const float* __restrict__ special,
        const float* __restrict__ lnw, const float* __restrict__ lnb,
        unsigned short* __restrict__ hb, float* __restrict__ gate) {
    int row = blockIdx.x;
    const float* xr = x + (size_t)row * CC;
    float s = 0.f, q = 0.f;
    for (int i = threadIdx.x; i < CC; i += 256) { float v = xr[i]; s += v; q += v * v; }
    for (int o = 32; o; o >>= 1) { s += __shfl_xor(s, o); q += __shfl_xor(q, o); }
    __shared__ float ss[4], sq[4];
    int wid = threadIdx.x >> 6;
    if ((threadIdx.x & 63) == 0) { ss[wid] = s; sq[wid] = q; }
    __syncthreads();
    s = ss[0] + ss[1] + ss[2] + ss[3];
    q = sq[0] + sq[1] + sq[2] + sq[3];
    float mu  = s * (1.f / CC);
    float var = fmaxf(q * (1.f / CC) - mu * mu, 0.f);
    float rstd = rsqrtf(var + 1e-12f);
    unsigned short* hr = hb + (size_t)row * CC;
    for (int i = threadIdx.x; i < CC; i += 256)
        hr[i] = f2bf((xr[i] - mu) * rstd * lnw[i] + lnb[i]);
    if (threadIdx.x == 0) gate[row] = (1.f - special[row]) * mask[row];
}

// ---------------- K2: reg_w[o][c][k] -> Wbt[kc][o][e] bf16  (kc = K/8, K = k*768+c) ----------------
__global__ __launch_bounds__(256) void k_wbt(const float* __restrict__ rw,
                                             unsigned short* __restrict__ wbt) {
    __shared__ float s[GK];
    int o = blockIdx.x;
    for (int i = threadIdx.x; i < GK; i += 256) s[i] = rw[(size_t)o * GK + i];
    __syncthreads();
    for (int kc = threadIdx.x; kc < NKC; kc += 256) {
        int k = kc / 96;               // tap
        int c0 = (kc - k * 96) * 8;    // channel base
        ushort8 r;
#pragma unroll
        for (int e = 0; e < 8; ++e) r[e] = f2bf(s[(c0 + e) * KHH + k]);
        *(ushort8*)(wbt + ((size_t)kc * CC + o) * 8) = r;
    }
}

// ---------------- K2b: conv weights -> wcb[i][c] bf16 ----------------
__global__ __launch_bounds__(256) void k_wcb(const float* __restrict__ ow, const float* __restrict__ mw,
                                             unsigned short* __restrict__ wcb) {
    int i = blockIdx.x;
    for (int c = threadIdx.x; c < CC; c += 256) {
        float v = 0.f;
        if (i < 49)      v = ow[(size_t)(i / 7) * (CC * KHH) + (size_t)c * KHH + (i % 7)];
        else if (i < 98) { int j = i - 49; v = mw[(size_t)(j / 7) * (CC * KHH) + (size_t)c * KHH + (j % 7)]; }
        wcb[(size_t)i * CC + c] = f2bf(v);
    }
}

// ---------------- K3: d[row][i] = sum_c hb[row][c] * wcb[i][c] ----------------
__global__ __launch_bounds__(256) void k_dg2(const unsigned short* __restrict__ A,
        const unsigned short* __restrict__ Bm, float* __restrict__ d) {
    __shared__ __align__(16) char As[128 * 128];
    __shared__ __align__(16) char Bs[128 * 128];
    int r0 = blockIdx.x * 128;
    int t = threadIdx.x;
    int lane = t & 63, w = t >> 6;
    int wr = w >> 1, wc = w & 1;
    f32x4 acc[4][4];
#pragma unroll
    for (int m = 0; m < 4; ++m)
#pragma unroll
        for (int n = 0; n < 4; ++n) acc[m][n] = (f32x4){0.f, 0.f, 0.f, 0.f};
    int lr = lane & 15;
    int lkb0 = (lane >> 4) * 16;
    for (int kk = 0; kk < CC; kk += 64) {
#pragma unroll
        for (int s = 0; s < 4; ++s) {
            int byteoff = (s * 256 + t) * 16;
            int row = byteoff >> 7;
            int colb = byteoff & 127;
            int sw = (row * 128 + colb) ^ ((row & 7) << 4);
            *(ushort8*)(As + sw) = *(const ushort8*)(A + (size_t)(r0 + row) * CC + kk + (colb >> 1));
            *(ushort8*)(Bs + sw) = *(const ushort8*)(Bm + (size_t)row * CC + kk + (colb >> 1));
        }
        __syncthreads();
#pragma unroll
        for (int ks = 0; ks < 2; ++ks) {
            short8 av[4], bv[4];
            int lkb = lkb0 + ks * 64;
#pragma unroll
            for (int m = 0; m < 4; ++m) {
                int ar = wr * 64 + m * 16 + lr;
                av[m] = *(const short8*)(As + ((ar * 128 + lkb) ^ ((ar & 7) << 4)));
            }
#pragma unroll
            for (int n = 0; n < 4; ++n) {
                int br = wc * 64 + n * 16 + lr;
                bv[n] = *(const short8*)(Bs + ((br * 128 + lkb) ^ ((br & 7) << 4)));
            }
#pragma unroll
            for (int m = 0; m < 4; ++m)
#pragma unroll
                for (int n = 0; n < 4; ++n)
                    acc[m][n] = __builtin_amdgcn_mfma_f32_16x16x32_bf16(av[m], bv[n], acc[m][n], 0, 0, 0);
        }
        __syncthreads();
    }
    int lr4 = (lane >> 4) * 4, lc = lane & 15;
#pragma unroll
    for (int m = 0; m < 4; ++m) {
        int gr = r0 + wr * 64 + m * 16 + lr4;
#pragma unroll
        for (int n = 0; n < 4; ++n) {
            int gc = wc * 64 + n * 16 + lc;
#pragma unroll
            for (int j = 0; j < 4; ++j)
                d[(size_t)(gr + j) * 128 + gc] = acc[m][n][j];
        }
    }
}

// ---------------- K4: sampling params ----------------
__global__ __launch_bounds__(256) void k_off(const float* __restrict__ d,
        const float* __restrict__ offb, const float* __restrict__ modb,
        const float* __restrict__ gate,
        int* __restrict__ idx0, int* __restrict__ idx1,
        float* __restrict__ w0a, float* __restrict__ w1a) {
    int flat = blockIdx.x * 256 + threadIdx.x;   // b*7*L + k*L + p
    if (flat >= NKP) return;
    int p = flat & (LL - 1);
    int k = (flat >> 12) % KHH;
    int b = flat / (KHH * LL);
    float offa = offb[k], moda = modb[k];
#pragma unroll
    for (int j = 0; j < KHH; ++j) {
        int q = p + j - PADK;
        if (q >= 0 && q < LL) {
            const float* dr = d + (size_t)(b * LL + q) * 128;
            offa += dr[k * 7 + j];
            moda += dr[49 + k * 7 + j];
        }
    }
    float modv = 2.f / (1.f + expf(-moda));
    float pos = (float)(p - PADK + k) + offa;
    pos = fminf(fmaxf(pos, -1.0e9f), 1.0e9f);
    float f = floorf(pos);
    float tf = pos - f;
    int i0 = (int)f;
    int i1 = i0 + 1;
    float in0 = (i0 >= 0 && i0 < LL) ? 1.f : 0.f;
    float in1 = (i1 >= 0 && i1 < LL) ? 1.f : 0.f;
    int c0 = min(max(i0, 0), LL - 1);
    int c1 = min(max(i1, 0), LL - 1);
    float g0 = gate[b * LL + c0] * in0;
    float g1 = gate[b * LL + c1] * in1;
    w0a[flat] = modv * (1.f - tf) * g0;
    w1a[flat] = modv * tf * g1;
    idx0[flat] = c0;
    idx1[flat] = c1;
}

// ---------------- K5: fused sample+GEMM; BM=64, 8 waves x (64x48 strip), 16 waves/CU ----------------
// BM=64, BN=384, BK=64; 512 threads = 8 waves (1x8); grid 512 = 2 blocks/CU = 4 waves/SIMD

#define STEPOFF 49152   // 8 kc per step * 768 * 8 elems
#define KSOFF   24576   // 4 kc * 768 * 8 elems

#define LOADB3(Q, KS, D0, D1, D2) do { \
    const unsigned short* _q = (Q) + (KS) * KSOFF; \
    D0 = *(const short8*)(_q); \
    D1 = *(const short8*)(_q + 128); \
    D2 = *(const short8*)(_q + 256); \
} while (0)

#define MFMA_ROW3(AV, M, B0, B1, B2) \
    acc[M][0] = __builtin_amdgcn_mfma_f32_16x16x32_bf16(AV, B0, acc[M][0], 0, 0, 0); \
    acc[M][1] = __builtin_amdgcn_mfma_f32_16x16x32_bf16(AV, B1, acc[M][1], 0, 0, 0); \
    acc[M][2] = __builtin_amdgcn_mfma_f32_16x16x32_bf16(AV, B2, acc[M][2], 0, 0, 0);

#define COMPUTE_KS3(ASB, KS, B0, B1, B2) do { \
    __builtin_amdgcn_s_setprio(1); \
    int _lkb = ke0 * 2 + (KS) * 64; \
    short8 _av0, _av1, _av2, _av3; \
    { int ar = 0 * 16 + lr; _av0 = *(const short8*)((ASB) + ar * 128 + (_lkb ^ ((ar & 7) << 4))); } \
    { int ar = 1 * 16 + lr; _av1 = *(const short8*)((ASB) + ar * 128 + (_lkb ^ ((ar & 7) << 4))); } \
    { int ar = 2 * 16 + lr; _av2 = *(const short8*)((ASB) + ar * 128 + (_lkb ^ ((ar & 7) << 4))); } \
    { int ar = 3 * 16 + lr; _av3 = *(const short8*)((ASB) + ar * 128 + (_lkb ^ ((ar & 7) << 4))); } \
    MFMA_ROW3(_av0, 0, B0, B1, B2) \
    MFMA_ROW3(_av1, 1, B0, B1, B2) \
    MFMA_ROW3(_av2, 2, B0, B1, B2) \
    MFMA_ROW3(_av3, 3, B0, B1, B2) \
    __builtin_amdgcn_s_setprio(0); \
} while (0)

// counted barrier (T4): LDS drained, global loads stay in flight across the barrier
#define BAR() do { \
    asm volatile("s_waitcnt lgkmcnt(0)" ::: "memory"); \
    __builtin_amdgcn_s_barrier(); \
    __builtin_amdgcn_sched_barrier(0); \
} while (0)

__global__ __launch_bounds__(512, 4) void k_fgemm(const unsigned short* __restrict__ hb,
        const unsigned short* __restrict__ Wbt,
        const int* __restrict__ idx0, const int* __restrict__ idx1,
        const float* __restrict__ w0a, const float* __restrict__ w1a,
        const float* __restrict__ resid, float* __restrict__ out) {
    __shared__ __align__(16) char As[2][64 * 128];   // 16 KB

    int bid = blockIdx.x;
    int nhalf = (bid & 7) >> 2;                 // XCDs 0-3 -> half 0, 4-7 -> half 1
    int rowtile = (bid >> 3) * 4 + (bid & 3);   // bijective 0..255
    int r0 = rowtile * 64;
    int o0 = nhalf * 384;
    int b = r0 >> 12;
    int p0 = r0 & (LL - 1);
    int pbase = ((b * KHH) << 12) + p0;
    const unsigned short* hbB = hb + (size_t)b * LL * CC;

    int t = threadIdx.x;
    int lane = t & 63, wc = t >> 6;             // wave 0..7 owns 48-col strip
    int lr = lane & 15;
    int ke0 = (lane >> 4) * 8;                  // elem offset of lane's 8-elem k-chunk

    // per-lane B base pointer into Wbt; advances STEPOFF per step
    const unsigned short* pB = Wbt + ((size_t)(lane >> 4) * CC + o0 + wc * 48 + lr) * 8;

    // A-build mapping: row = t>>3 (0..63), seg = t&7 (8 elems = 16 B each)
    int arow = t >> 3, aseg = t & 7;
    int aswz0 = arow * 128 + ((aseg * 16) ^ ((arow & 7) << 4));

    f32x4 acc[4][3];
#pragma unroll
    for (int m = 0; m < 4; ++m)
#pragma unroll
        for (int n = 0; n < 3; ++n) acc[m][n] = (f32x4){0.f, 0.f, 0.f, 0.f};

    // per-tap sampling regs
    int g0 = 0, g1 = 0;
    float wa = 0.f, wbv = 0.f;
    int cur_tap = -1;

    // staging registers (all individually named)
    ushort8 la0, la2;
    short8 S0_0, S0_1, S0_2;   // ks0 buffer (even steps)
    short8 S1_0, S1_1, S1_2;   // ks1 buffer (reloaded late every step)
    short8 S2_0, S2_1, S2_2;   // ks0 buffer (odd steps)

    auto loadA = [&](int tap, int c0) {
        if (tap != cur_tap) {
            int pf = pbase + (tap << 12) + arow;
            g0 = idx0[pf]; g1 = idx1[pf];
            wa = w0a[pf];  wbv = w1a[pf];
            cur_tap = tap;
        }
        la0 = *(const ushort8*)(hbB + (size_t)g0 * CC + c0 + aseg * 8);
        la2 = *(const ushort8*)(hbB + (size_t)g1 * CC + c0 + aseg * 8);
    };

    auto writeA = [&](char* Asb) {
        ushort8 ra;
#pragma unroll
        for (int e = 0; e < 8; ++e) ra[e] = f2bf(fmaf(wa, bf2f(la0[e]), wbv * bf2f(la2[e])));
        *(ushort8*)(Asb + aswz0) = ra;
    };

    // prologue: step 0 fully staged
    loadA(0, 0);
    LOADB3(pB, 0, S0_0, S0_1, S0_2);
    LOADB3(pB, 1, S1_0, S1_1, S1_2);
    writeA(As[0]);
    BAR();

    int tap_c = 0, c0_c = 0;
    for (int sp = 0; sp < NT; sp += 2) {
        // ---------------- even step s = sp (computes As[0], S0/S1) ----------------
        {
            int tap_n = tap_c, c0_n = c0_c + 64;
            if (c0_n == CC) { c0_n = 0; ++tap_n; }
            bool more = (sp + 1 < NT);
            const unsigned short* pN = pB + STEPOFF;
            if (more) {
                LOADB3(pN, 0, S2_0, S2_1, S2_2);
                loadA(tap_n, c0_n);
            }
            __builtin_amdgcn_sched_barrier(0);
            COMPUTE_KS3(As[0], 0, S0_0, S0_1, S0_2);
            COMPUTE_KS3(As[0], 1, S1_0, S1_1, S1_2);
            __builtin_amdgcn_sched_barrier(0);
            if (more) {
                LOADB3(pN, 1, S1_0, S1_1, S1_2);
                writeA(As[1]);
            }
            BAR();
            pB = pN;
            tap_c = tap_n; c0_c = c0_n;
        }
        // ---------------- odd step s = sp+1 (computes As[1], S2/S1) ----------------
        {
            int s = sp + 1;
            if (s >= NT) break;
            int tap_n = tap_c, c0_n = c0_c + 64;
            if (c0_n == CC) { c0_n = 0; ++tap_n; }
            bool more = (s + 1 < NT);
            const unsigned short* pN = pB + STEPOFF;
            if (more) {
                LOADB3(pN, 0, S0_0, S0_1, S0_2);
                loadA(tap_n, c0_n);
            }
            __builtin_amdgcn_sched_barrier(0);
            COMPUTE_KS3(As[1], 0, S2_0, S2_1, S2_2);
            COMPUTE_KS3(As[1], 1, S1_0, S1_1, S1_2);
            __builtin_amdgcn_sched_barrier(0);
            if (more) {
                LOADB3(pN, 1, S1_0, S1_1, S1_2);
                writeA(As[0]);
            }
            BAR();
            pB = pN;
            tap_c = tap_n; c0_c = c0_n;
        }
    }

    // epilogue: + residual
    int lr4 = (lane >> 4) * 4, lc = lane & 15;
#pragma unroll
    for (int m = 0; m < 4; ++m) {
        int gr = r0 + m * 16 + lr4;
#pragma unroll
        for (int n = 0; n < 3; ++n) {
            int gc = o0 + wc * 48 + n * 16 + lc;
#pragma unroll
            for (int j = 0; j < 4; ++j) {
                size_t idx = (size_t)(gr + j) * CC + gc;
                out[idx] = acc[m][n][j] + resid[idx];
            }
        }
    }
}

extern "C" void kernel_launch(void* const* d_in, const int* in_sizes, int n_in,
                              void* d_out, int out_size, void* d_ws, size_t ws_size,
                              hipStream_t stream) {
    const float* x   = (const float*)d_in[0];
    const float* am  = (const float*)d_in[1];
    const float* stm = (const float*)d_in[2];
    const float* lnw = (const float*)d_in[3];
    const float* lnb = (const float*)d_in[4];
    const float* ow  = (const float*)d_in[5];
    const float* ob  = (const float*)d_in[6];
    const float* mw  = (const float*)d_in[7];
    const float* mb  = (const float*)d_in[8];
    const float* rw  = (const float*)d_in[9];
    float* out = (float*)d_out;

    char* ws = (char*)d_ws;
    size_t off = 0;
    auto carve = [&](size_t bytes) -> char* {
        char* p = ws + off;
        off += (bytes + 255) & ~(size_t)255;
        return p;
    };
    unsigned short* hb  = (unsigned short*)carve((size_t)ROWS * CC * 2);   // 25.2 MB
    unsigned short* wbt = (unsigned short*)carve((size_t)NKC * CC * 8 * 2);// 8.25 MB
    unsigned short* wcb = (unsigned short*)carve((size_t)128 * CC * 2);    // 0.20 MB
    float* d    = (float*)carve((size_t)ROWS * 128 * 4);                   // 8.4 MB
    float* gate = (float*)carve((size_t)ROWS * 4);
    int*   i0   = (int*)carve((size_t)NKP * 4);
    int*   i1   = (int*)carve((size_t)NKP * 4);
    float* w0   = (float*)carve((size_t)NKP * 4);
    float* w1   = (float*)carve((size_t)NKP * 4);

    k_ln<<<ROWS, 256, 0, stream>>>(x, am, stm, lnw, lnb, hb, gate);
    k_wbt<<<CC, 256, 0, stream>>>(rw, wbt);
    k_wcb<<<128, 256, 0, stream>>>(ow, mw, wcb);
    k_dg2<<<ROWS / 128, 256, 0, stream>>>(hb, wcb, d);
    k_off<<<NKP / 256, 256, 0, stream>>>(d, ob, mb, gate, i0, i1, w0, w1);
    k_fgemm<<<512, 512, 0, stream>>>(hb, wbt, i0, i1, w0, w1, x, out);
}

// Round 15
// 196.673 us; speedup vs baseline: 1.1128x; 1.0971x over previous
//
#include <hip/hip_runtime.h>
#include <math.h>

#define BB 4
#define LL 4096
#define CC 768
#define KHH 7
#define PADK 3
#define ROWS (BB*LL)      // 16384
#define NKP  (BB*KHH*LL)  // 114688
#define GK   (KHH*CC)     // 5376
#define NT   (GK/64)      // 84
#define NKC  (GK/8)       // 672

typedef unsigned short ushort8 __attribute__((ext_vector_type(8)));
typedef short short8 __attribute__((ext_vector_type(8)));
typedef float f32x4 __attribute__((ext_vector_type(4)));
typedef unsigned int uint4v __attribute__((ext_vector_type(4)));

__device__ __forceinline__ float bf2f(unsigned short u) {
    return __uint_as_float(((unsigned)u) << 16);
}
__device__ __forceinline__ unsigned short f2bf(float x) {
    unsigned u = __float_as_uint(x);
    return (unsigned short)((u + 0x7FFFu + ((u >> 16) & 1u)) >> 16);
}
__device__ __forceinline__ unsigned cvtpk(float lo, float hi) {
    unsigned r;
    asm("v_cvt_pk_bf16_f32 %0, %1, %2" : "=v"(r) : "v"(lo), "v"(hi));
    return r;
}

// ---------------- K1: layernorm + gate -> h_bf16 ----------------
__global__ __launch_bounds__(256) void k_ln(const float* __restrict__ x,
        const float* __restrict__ mask, const float* __restrict__ special,
        const float* __restrict__ lnw, const float* __restrict__ lnb,
        unsigned short* __restrict__ hb, float* __restrict__ gate) {
    int row = blockIdx.x;
    const float* xr = x + (size_t)row * CC;
    float s = 0.f, q = 0.f;
    for (int i = threadIdx.x; i < CC; i += 256) { float v = xr[i]; s += v; q += v * v; }
    for (int o = 32; o; o >>= 1) { s += __shfl_xor(s, o); q += __shfl_xor(q, o); }
    __shared__ float ss[4], sq[4];
    int wid = threadIdx.x >> 6;
    if ((threadIdx.x & 63) == 0) { ss[wid] = s; sq[wid] = q; }
    __syncthreads();
    s = ss[0] + ss[1] + ss[2] + ss[3];
    q = sq[0] + sq[1] + sq[2] + sq[3];
    float mu  = s * (1.f / CC);
    float var = fmaxf(q * (1.f / CC) - mu * mu, 0.f);
    float rstd = rsqrtf(var + 1e-12f);
    unsigned short* hr = hb + (size_t)row * CC;
    for (int i = threadIdx.x; i < CC; i += 256)
        hr[i] = f2bf((xr[i] - mu) * rstd * lnw[i] + lnb[i]);
    if (threadIdx.x == 0) gate[row] = (1.f - special[row]) * mask[row];
}

// ---------------- K2: reg_w[o][c][k] -> Wbt[kc][o][e] bf16  (kc = K/8, K = k*768+c) ----------------
__global__ __launch_bounds__(256) void k_wbt(const float* __restrict__ rw,
                                             unsigned short* __restrict__ wbt) {
    __shared__ float s[GK];
    int o = blockIdx.x;
    for (int i = threadIdx.x; i < GK; i += 256) s[i] = rw[(size_t)o * GK + i];
    __syncthreads();
    for (int kc = threadIdx.x; kc < NKC; kc += 256) {
        int k = kc / 96;               // tap
        int c0 = (kc - k * 96) * 8;    // channel base
        ushort8 r;
#pragma unroll
        for (int e = 0; e < 8; ++e) r[e] = f2bf(s[(c0 + e) * KHH + k]);
        *(ushort8*)(wbt + ((size_t)kc * CC + o) * 8) = r;
    }
}

// ---------------- K2b: conv weights -> wcb[i][c] bf16 ----------------
__global__ __launch_bounds__(256) void k_wcb(const float* __restrict__ ow, const float* __restrict__ mw,
                                             unsigned short* __restrict__ wcb) {
    int i = blockIdx.x;
    for (int c = threadIdx.x; c < CC; c += 256) {
        float v = 0.f;
        if (i < 49)      v = ow[(size_t)(i / 7) * (CC * KHH) + (size_t)c * KHH + (i % 7)];
        else if (i < 98) { int j = i - 49; v = mw[(size_t)(j / 7) * (CC * KHH) + (size_t)c * KHH + (j % 7)]; }
        wcb[(size_t)i * CC + c] = f2bf(v);
    }
}

// ---------------- K3: d[row][i] = sum_c hb[row][c] * wcb[i][c] ----------------
__global__ __launch_bounds__(256) void k_dg2(const unsigned short* __restrict__ A,
        const unsigned short* __restrict__ Bm, float* __restrict__ d) {
    __shared__ __align__(16) char As[128 * 128];
    __shared__ __align__(16) char Bs[128 * 128];
    int r0 = blockIdx.x * 128;
    int t = threadIdx.x;
    int lane = t & 63, w = t >> 6;
    int wr = w >> 1, wc = w & 1;
    f32x4 acc[4][4];
#pragma unroll
    for (int m = 0; m < 4; ++m)
#pragma unroll
        for (int n = 0; n < 4; ++n) acc[m][n] = (f32x4){0.f, 0.f, 0.f, 0.f};
    int lr = lane & 15;
    int lkb0 = (lane >> 4) * 16;
    for (int kk = 0; kk < CC; kk += 64) {
#pragma unroll
        for (int s = 0; s < 4; ++s) {
            int byteoff = (s * 256 + t) * 16;
            int row = byteoff >> 7;
            int colb = byteoff & 127;
            int sw = (row * 128 + colb) ^ ((row & 7) << 4);
            *(ushort8*)(As + sw) = *(const ushort8*)(A + (size_t)(r0 + row) * CC + kk + (colb >> 1));
            *(ushort8*)(Bs + sw) = *(const ushort8*)(Bm + (size_t)row * CC + kk + (colb >> 1));
        }
        __syncthreads();
#pragma unroll
        for (int ks = 0; ks < 2; ++ks) {
            short8 av[4], bv[4];
            int lkb = lkb0 + ks * 64;
#pragma unroll
            for (int m = 0; m < 4; ++m) {
                int ar = wr * 64 + m * 16 + lr;
                av[m] = *(const short8*)(As + ((ar * 128 + lkb) ^ ((ar & 7) << 4)));
            }
#pragma unroll
            for (int n = 0; n < 4; ++n) {
                int br = wc * 64 + n * 16 + lr;
                bv[n] = *(const short8*)(Bs + ((br * 128 + lkb) ^ ((br & 7) << 4)));
            }
#pragma unroll
            for (int m = 0; m < 4; ++m)
#pragma unroll
                for (int n = 0; n < 4; ++n)
                    acc[m][n] = __builtin_amdgcn_mfma_f32_16x16x32_bf16(av[m], bv[n], acc[m][n], 0, 0, 0);
        }
        __syncthreads();
    }
    int lr4 = (lane >> 4) * 4, lc = lane & 15;
#pragma unroll
    for (int m = 0; m < 4; ++m) {
        int gr = r0 + wr * 64 + m * 16 + lr4;
#pragma unroll
        for (int n = 0; n < 4; ++n) {
            int gc = wc * 64 + n * 16 + lc;
#pragma unroll
            for (int j = 0; j < 4; ++j)
                d[(size_t)(gr + j) * 128 + gc] = acc[m][n][j];
        }
    }
}

// ---------------- K4: sampling params ----------------
__global__ __launch_bounds__(256) void k_off(const float* __restrict__ d,
        const float* __restrict__ offb, const float* __restrict__ modb,
        const float* __restrict__ gate,
        int* __restrict__ idx0, int* __restrict__ idx1,
        float* __restrict__ w0a, float* __restrict__ w1a) {
    int flat = blockIdx.x * 256 + threadIdx.x;   // b*7*L + k*L + p
    if (flat >= NKP) return;
    int p = flat & (LL - 1);
    int k = (flat >> 12) % KHH;
    int b = flat / (KHH * LL);
    float offa = offb[k], moda = modb[k];
#pragma unroll
    for (int j = 0; j < KHH; ++j) {
        int q = p + j - PADK;
        if (q >= 0 && q < LL) {
            const float* dr = d + (size_t)(b * LL + q) * 128;
            offa += dr[k * 7 + j];
            moda += dr[49 + k * 7 + j];
        }
    }
    float modv = 2.f / (1.f + expf(-moda));
    float pos = (float)(p - PADK + k) + offa;
    pos = fminf(fmaxf(pos, -1.0e9f), 1.0e9f);
    float f = floorf(pos);
    float tf = pos - f;
    int i0 = (int)f;
    int i1 = i0 + 1;
    float in0 = (i0 >= 0 && i0 < LL) ? 1.f : 0.f;
    float in1 = (i1 >= 0 && i1 < LL) ? 1.f : 0.f;
    int c0 = min(max(i0, 0), LL - 1);
    int c1 = min(max(i1, 0), LL - 1);
    float g0 = gate[b * LL + c0] * in0;
    float g1 = gate[b * LL + c1] * in1;
    w0a[flat] = modv * (1.f - tf) * g0;
    w1a[flat] = modv * tf * g1;
    idx0[flat] = c0;
    idx1[flat] = c1;
}

// ---------------- K5: fused sample+GEMM; 8 waves x (128x48 strip), cvt_pk lerp, open scheduling ----------------
// BM=128, BN=384, BK=64; 512 threads = 8 waves (1x8), wave strip 128x48 = 8x3 frags 16x16x32

#define STEPOFF 49152   // 8 kc per step * 768 * 8 elems
#define KSOFF   24576   // 4 kc * 768 * 8 elems

#define LOADB3(Q, KS, D0, D1, D2) do { \
    const unsigned short* _q = (Q) + (KS) * KSOFF; \
    D0 = *(const short8*)(_q); \
    D1 = *(const short8*)(_q + 128); \
    D2 = *(const short8*)(_q + 256); \
} while (0)

#define MFMA_ROW3(AV, M, B0, B1, B2) \
    acc[M][0] = __builtin_amdgcn_mfma_f32_16x16x32_bf16(AV, B0, acc[M][0], 0, 0, 0); \
    acc[M][1] = __builtin_amdgcn_mfma_f32_16x16x32_bf16(AV, B1, acc[M][1], 0, 0, 0); \
    acc[M][2] = __builtin_amdgcn_mfma_f32_16x16x32_bf16(AV, B2, acc[M][2], 0, 0, 0);

#define COMPUTE_KS3(ASB, KS, B0, B1, B2) do { \
    __builtin_amdgcn_s_setprio(1); \
    int _lkb = ke0 * 2 + (KS) * 64; \
    short8 _av0, _av1, _av2, _av3, _av4, _av5, _av6, _av7; \
    { int ar = 0 * 16 + lr; _av0 = *(const short8*)((ASB) + ar * 128 + (_lkb ^ ((ar & 7) << 4))); } \
    { int ar = 1 * 16 + lr; _av1 = *(const short8*)((ASB) + ar * 128 + (_lkb ^ ((ar & 7) << 4))); } \
    { int ar = 2 * 16 + lr; _av2 = *(const short8*)((ASB) + ar * 128 + (_lkb ^ ((ar & 7) << 4))); } \
    { int ar = 3 * 16 + lr; _av3 = *(const short8*)((ASB) + ar * 128 + (_lkb ^ ((ar & 7) << 4))); } \
    MFMA_ROW3(_av0, 0, B0, B1, B2) \
    MFMA_ROW3(_av1, 1, B0, B1, B2) \
    MFMA_ROW3(_av2, 2, B0, B1, B2) \
    MFMA_ROW3(_av3, 3, B0, B1, B2) \
    { int ar = 4 * 16 + lr; _av4 = *(const short8*)((ASB) + ar * 128 + (_lkb ^ ((ar & 7) << 4))); } \
    { int ar = 5 * 16 + lr; _av5 = *(const short8*)((ASB) + ar * 128 + (_lkb ^ ((ar & 7) << 4))); } \
    { int ar = 6 * 16 + lr; _av6 = *(const short8*)((ASB) + ar * 128 + (_lkb ^ ((ar & 7) << 4))); } \
    { int ar = 7 * 16 + lr; _av7 = *(const short8*)((ASB) + ar * 128 + (_lkb ^ ((ar & 7) << 4))); } \
    MFMA_ROW3(_av4, 4, B0, B1, B2) \
    MFMA_ROW3(_av5, 5, B0, B1, B2) \
    MFMA_ROW3(_av6, 6, B0, B1, B2) \
    MFMA_ROW3(_av7, 7, B0, B1, B2) \
    __builtin_amdgcn_s_setprio(0); \
} while (0)

// counted barrier (T4): LDS drained, global loads stay in flight across the barrier
#define BAR() do { \
    asm volatile("s_waitcnt lgkmcnt(0)" ::: "memory"); \
    __builtin_amdgcn_s_barrier(); \
    __builtin_amdgcn_sched_barrier(0); \
} while (0)

__global__ __launch_bounds__(512, 2) void k_fgemm(const unsigned short* __restrict__ hb,
        const unsigned short* __restrict__ Wbt,
        const int* __restrict__ idx0, const int* __restrict__ idx1,
        const float* __restrict__ w0a, const float* __restrict__ w1a,
        const float* __restrict__ resid, float* __restrict__ out) {
    __shared__ __align__(16) char As[2][128 * 128];

    int bid = blockIdx.x;
    int nhalf = (bid & 7) >> 2;                 // XCDs 0-3 -> half 0, 4-7 -> half 1
    int rowtile = (bid >> 3) * 4 + (bid & 3);   // bijective 0..127
    int r0 = rowtile * 128;
    int o0 = nhalf * 384;
    int b = r0 >> 12;
    int p0 = r0 & (LL - 1);
    int pbase = ((b * KHH) << 12) + p0;
    const unsigned short* hbB = hb + (size_t)b * LL * CC;

    int t = threadIdx.x;
    int lane = t & 63, wc = t >> 6;             // wave 0..7 owns 48-col strip
    int lr = lane & 15;
    int ke0 = (lane >> 4) * 8;     // elem offset of lane's 8-elem k-chunk

    // per-lane B base pointer into Wbt; advances STEPOFF per step
    const unsigned short* pB = Wbt + ((size_t)(lane >> 4) * CC + o0 + wc * 48 + lr) * 8;

    // A-build mapping: row = t>>2 (0..127), seg = t&3 (16 elems each)
    int arow = t >> 2, aseg = t & 3;
    int acolb = aseg * 32;
    int aswz0 = arow * 128 + (acolb ^ ((arow & 7) << 4));
    int aswz1 = arow * 128 + ((acolb + 16) ^ ((arow & 7) << 4));

    f32x4 acc[8][3];
#pragma unroll
    for (int m = 0; m < 8; ++m)
#pragma unroll
        for (int n = 0; n < 3; ++n) acc[m][n] = (f32x4){0.f, 0.f, 0.f, 0.f};

    // per-tap sampling regs + incremental gather pointers
    float wa = 0.f, wbv = 0.f;
    int cur_tap = -1;
    const unsigned short* pA0 = hbB;
    const unsigned short* pA1 = hbB;

    // staging registers (all individually named)
    ushort8 la0, la1, la2, la3;
    short8 S0_0, S0_1, S0_2;   // ks0 buffer (even steps)
    short8 S1_0, S1_1, S1_2;   // ks1 buffer (reloaded late every step)
    short8 S2_0, S2_1, S2_2;   // ks0 buffer (odd steps)

    auto loadA = [&](int tap, int c0) {
        if (tap != cur_tap) {
            int pf = pbase + (tap << 12) + arow;
            int g0 = idx0[pf], g1 = idx1[pf];
            wa = w0a[pf];  wbv = w1a[pf];
            cur_tap = tap;
            pA0 = hbB + (size_t)g0 * CC + c0 + aseg * 16;
            pA1 = hbB + (size_t)g1 * CC + c0 + aseg * 16;
        } else {
            pA0 += 64;
            pA1 += 64;
        }
        la0 = *(const ushort8*)(pA0);
        la1 = *(const ushort8*)(pA0 + 8);
        la2 = *(const ushort8*)(pA1);
        la3 = *(const ushort8*)(pA1 + 8);
    };

    auto writeA = [&](char* Asb) {
        uint4v va, vb;
#pragma unroll
        for (int p = 0; p < 4; ++p) {
            float lo = fmaf(wa, bf2f(la0[2 * p]),     wbv * bf2f(la2[2 * p]));
            float hi = fmaf(wa, bf2f(la0[2 * p + 1]), wbv * bf2f(la2[2 * p + 1]));
            va[p] = cvtpk(lo, hi);
        }
#pragma unroll
        for (int p = 0; p < 4; ++p) {
            float lo = fmaf(wa, bf2f(la1[2 * p]),     wbv * bf2f(la3[2 * p]));
            float hi = fmaf(wa, bf2f(la1[2 * p + 1]), wbv * bf2f(la3[2 * p + 1]));
            vb[p] = cvtpk(lo, hi);
        }
        *(uint4v*)(Asb + aswz0) = va;
        *(uint4v*)(Asb + aswz1) = vb;
    };

    // prologue: step 0 fully staged
    loadA(0, 0);
    LOADB3(pB, 0, S0_0, S0_1, S0_2);
    LOADB3(pB, 1, S1_0, S1_1, S1_2);
    writeA(As[0]);
    BAR();

    int tap_c = 0, c0_c = 0;
    for (int sp = 0; sp < NT; sp += 2) {
        // ---------------- even step s = sp (computes As[0], S0/S1) ----------------
        {
            int tap_n = tap_c, c0_n = c0_c + 64;
            if (c0_n == CC) { c0_n = 0; ++tap_n; }
            bool more = (sp + 1 < NT);
            const unsigned short* pN = pB + STEPOFF;
            if (more) {
                LOADB3(pN, 0, S2_0, S2_1, S2_2);
                loadA(tap_n, c0_n);
            }
            __builtin_amdgcn_sched_barrier(0);
            COMPUTE_KS3(As[0], 0, S0_0, S0_1, S0_2);
            COMPUTE_KS3(As[0], 1, S1_0, S1_1, S1_2);
            if (more) {
                LOADB3(pN, 1, S1_0, S1_1, S1_2);
                writeA(As[1]);
            }
            BAR();
            pB = pN;
            tap_c = tap_n; c0_c = c0_n;
        }
        // ---------------- odd step s = sp+1 (computes As[1], S2/S1) ----------------
        {
            int s = sp + 1;
            if (s >= NT) break;
            int tap_n = tap_c, c0_n = c0_c + 64;
            if (c0_n == CC) { c0_n = 0; ++tap_n; }
            bool more = (s + 1 < NT);
            const unsigned short* pN = pB + STEPOFF;
            if (more) {
                LOADB3(pN, 0, S0_0, S0_1, S0_2);
                loadA(tap_n, c0_n);
            }
            __builtin_amdgcn_sched_barrier(0);
            COMPUTE_KS3(As[1], 0, S2_0, S2_1, S2_2);
            COMPUTE_KS3(As[1], 1, S1_0, S1_1, S1_2);
            if (more) {
                LOADB3(pN, 1, S1_0, S1_1, S1_2);
                writeA(As[0]);
            }
            BAR();
            pB = pN;
            tap_c = tap_n; c0_c = c0_n;
        }
    }

    // epilogue: + residual
    int lr4 = (lane >> 4) * 4, lc = lane & 15;
#pragma unroll
    for (int m = 0; m < 8; ++m) {
        int gr = r0 + m * 16 + lr4;
#pragma unroll
        for (int n = 0; n < 3; ++n) {
            int gc = o0 + wc * 48 + n * 16 + lc;
#pragma unroll
            for (int j = 0; j < 4; ++j) {
                size_t idx = (size_t)(gr + j) * CC + gc;
                out[idx] = acc[m][n][j] + resid[idx];
            }
        }
    }
}

extern "C" void kernel_launch(void* const* d_in, const int* in_sizes, int n_in,
                              void* d_out, int out_size, void* d_ws, size_t ws_size,
                              hipStream_t stream) {
    const float* x   = (const float*)d_in[0];
    const float* am  = (const float*)d_in[1];
    const float* stm = (const float*)d_in[2];
    const float* lnw = (const float*)d_in[3];
    const float* lnb = (const float*)d_in[4];
    const float* ow  = (const float*)d_in[5];
    const float* ob  = (const float*)d_in[6];
    const float* mw  = (const float*)d_in[7];
    const float* mb  = (const float*)d_in[8];
    const float* rw  = (const float*)d_in[9];
    float* out = (float*)d_out;

    char* ws = (char*)d_ws;
    size_t off = 0;
    auto carve = [&](size_t bytes) -> char* {
        char* p = ws + off;
        off += (bytes + 255) & ~(size_t)255;
        return p;
    };
    unsigned short* hb  = (unsigned short*)carve((size_t)ROWS * CC * 2);   // 25.2 MB
    unsigned short* wbt = (unsigned short*)carve((size_t)NKC * CC * 8 * 2);// 8.25 MB
    unsigned short* wcb = (unsigned short*)carve((size_t)128 * CC * 2);    // 0.20 MB
    float* d    = (float*)carve((size_t)ROWS * 128 * 4);                   // 8.4 MB
    float* gate = (float*)carve((size_t)ROWS * 4);
    int*   i0   = (int*)carve((size_t)NKP * 4);
    int*   i1   = (int*)carve((size_t)NKP * 4);
    float* w0   = (float*)carve((size_t)NKP * 4);
    float* w1   = (float*)carve((size_t)NKP * 4);

    k_ln<<<ROWS, 256, 0, stream>>>(x, am, stm, lnw, lnb, hb, gate);
    k_wbt<<<CC, 256, 0, stream>>>(rw, wbt);
    k_wcb<<<128, 256, 0, stream>>>(ow, mw, wcb);
    k_dg2<<<ROWS / 128, 256, 0, stream>>>(hb, wcb, d);
    k_off<<<NKP / 256, 256, 0, stream>>>(d, ob, mb, gate, i0, i1, w0, w1);
    k_fgemm<<<256, 512, 0, stream>>>(hb, wbt, i0, i1, w0, w1, x, out);
}

// Round 16
// 184.864 us; speedup vs baseline: 1.1838x; 1.0639x over previous
//
#include <hip/hip_runtime.h>
#include <math.h>

#define BB 4
#define LL 4096
#define CC 768
#define KHH 7
#define PADK 3
#define ROWS (BB*LL)      // 16384
#define NKP  (BB*KHH*LL)  // 114688
#define GK   (KHH*CC)     // 5376
#define NT   (GK/64)      // 84
#define NKC  (GK/8)       // 672

typedef unsigned short ushort8 __attribute__((ext_vector_type(8)));
typedef unsigned short ushort4v __attribute__((ext_vector_type(4)));
typedef short short8 __attribute__((ext_vector_type(8)));
typedef float f32x4 __attribute__((ext_vector_type(4)));
typedef unsigned int uint4v __attribute__((ext_vector_type(4)));

__device__ __forceinline__ float bf2f(unsigned short u) {
    return __uint_as_float(((unsigned)u) << 16);
}
__device__ __forceinline__ unsigned short f2bf(float x) {
    unsigned u = __float_as_uint(x);
    return (unsigned short)((u + 0x7FFFu + ((u >> 16) & 1u)) >> 16);
}
__device__ __forceinline__ unsigned cvtpk(float lo, float hi) {
    unsigned r;
    asm("v_cvt_pk_bf16_f32 %0, %1, %2" : "=v"(r) : "v"(lo), "v"(hi));
    return r;
}

// ---------------- K1: layernorm + gate -> h_bf16 (1 wave/row, float4 loads, ushort4 stores) ----------------
__global__ __launch_bounds__(64) void k_ln(const float* __restrict__ x,
        const float* __restrict__ mask, const float* __restrict__ special,
        const float* __restrict__ lnw, const float* __restrict__ lnb,
        unsigned short* __restrict__ hb, float* __restrict__ gate) {
    int row = blockIdx.x;
    int t = threadIdx.x;
    const float4* xr = (const float4*)(x + (size_t)row * CC);
    float4 v0 = xr[t], v1 = xr[t + 64], v2 = xr[t + 128];
    float s = v0.x + v0.y + v0.z + v0.w
            + v1.x + v1.y + v1.z + v1.w
            + v2.x + v2.y + v2.z + v2.w;
    float q = v0.x * v0.x + v0.y * v0.y + v0.z * v0.z + v0.w * v0.w
            + v1.x * v1.x + v1.y * v1.y + v1.z * v1.z + v1.w * v1.w
            + v2.x * v2.x + v2.y * v2.y + v2.z * v2.z + v2.w * v2.w;
    for (int o = 32; o; o >>= 1) { s += __shfl_xor(s, o); q += __shfl_xor(q, o); }
    float mu  = s * (1.f / CC);
    float var = fmaxf(q * (1.f / CC) - mu * mu, 0.f);
    float rstd = rsqrtf(var + 1e-12f);
    const float4* lw = (const float4*)lnw;
    const float4* lb = (const float4*)lnb;
    ushort4v* hr = (ushort4v*)(hb + (size_t)row * CC);
#pragma unroll
    for (int j = 0; j < 3; ++j) {
        int i4 = t + 64 * j;
        float4 v = (j == 0) ? v0 : (j == 1) ? v1 : v2;
        float4 w = lw[i4], bso = lb[i4];
        ushort4v r;
        r[0] = f2bf((v.x - mu) * rstd * w.x + bso.x);
        r[1] = f2bf((v.y - mu) * rstd * w.y + bso.y);
        r[2] = f2bf((v.z - mu) * rstd * w.z + bso.z);
        r[3] = f2bf((v.w - mu) * rstd * w.w + bso.w);
        hr[i4] = r;
    }
    if (t == 0) gate[row] = (1.f - special[row]) * mask[row];
}

// ---------------- K2: reg_w[o][c][k] -> Wbt[kc][o][e] bf16 (coalesced both sides, 4 o/block) ----------------
__global__ __launch_bounds__(256) void k_wbt(const float* __restrict__ rw,
                                             unsigned short* __restrict__ wbt) {
    __shared__ float s[4 * GK];   // 86 KB
    int o0 = blockIdx.x * 4;
    for (int i = threadIdx.x; i < 4 * GK; i += 256)
        s[i] = rw[(size_t)(o0 + i / GK) * GK + (i % GK)];
    __syncthreads();
    for (int kc = threadIdx.x; kc < NKC; kc += 256) {
        int k = kc / 96;               // tap
        int c0 = (kc - k * 96) * 8;    // channel base
        unsigned short* dst = wbt + ((size_t)kc * CC + o0) * 8;
#pragma unroll
        for (int oo = 0; oo < 4; ++oo) {
            ushort8 r;
#pragma unroll
            for (int e = 0; e < 8; ++e) r[e] = f2bf(s[oo * GK + (c0 + e) * KHH + k]);
            *(ushort8*)(dst + oo * 8) = r;
        }
    }
}

// ---------------- K2b: conv weights -> wcb[i][c] bf16 ----------------
__global__ __launch_bounds__(256) void k_wcb(const float* __restrict__ ow, const float* __restrict__ mw,
                                             unsigned short* __restrict__ wcb) {
    int i = blockIdx.x;
    for (int c = threadIdx.x; c < CC; c += 256) {
        float v = 0.f;
        if (i < 49)      v = ow[(size_t)(i / 7) * (CC * KHH) + (size_t)c * KHH + (i % 7)];
        else if (i < 98) { int j = i - 49; v = mw[(size_t)(j / 7) * (CC * KHH) + (size_t)c * KHH + (j % 7)]; }
        wcb[(size_t)i * CC + c] = f2bf(v);
    }
}

// ---------------- K3: d[row][i] = sum_c hb[row][c] * wcb[i][c]  (BM=64 -> 256 blocks) ----------------
__global__ __launch_bounds__(256) void k_dg2(const unsigned short* __restrict__ A,
        const unsigned short* __restrict__ Bm, float* __restrict__ d) {
    __shared__ __align__(16) char As[64 * 128];
    __shared__ __align__(16) char Bs[128 * 128];
    int r0 = blockIdx.x * 64;
    int t = threadIdx.x;
    int lane = t & 63, w = t >> 6;
    int wr = w >> 1, wc = w & 1;
    f32x4 acc[2][4];
#pragma unroll
    for (int m = 0; m < 2; ++m)
#pragma unroll
        for (int n = 0; n < 4; ++n) acc[m][n] = (f32x4){0.f, 0.f, 0.f, 0.f};
    int lr = lane & 15;
    int lkb0 = (lane >> 4) * 16;
    for (int kk = 0; kk < CC; kk += 64) {
#pragma unroll
        for (int s = 0; s < 2; ++s) {
            int byteoff = (s * 256 + t) * 16;
            int row = byteoff >> 7;
            int colb = byteoff & 127;
            int sw = (row * 128 + colb) ^ ((row & 7) << 4);
            *(ushort8*)(As + sw) = *(const ushort8*)(A + (size_t)(r0 + row) * CC + kk + (colb >> 1));
        }
#pragma unroll
        for (int s = 0; s < 4; ++s) {
            int byteoff = (s * 256 + t) * 16;
            int row = byteoff >> 7;
            int colb = byteoff & 127;
            int sw = (row * 128 + colb) ^ ((row & 7) << 4);
            *(ushort8*)(Bs + sw) = *(const ushort8*)(Bm + (size_t)row * CC + kk + (colb >> 1));
        }
        __syncthreads();
#pragma unroll
        for (int ks = 0; ks < 2; ++ks) {
            short8 av[2], bv[4];
            int lkb = lkb0 + ks * 64;
#pragma unroll
            for (int m = 0; m < 2; ++m) {
                int ar = wr * 32 + m * 16 + lr;
                av[m] = *(const short8*)(As + ((ar * 128 + lkb) ^ ((ar & 7) << 4)));
            }
#pragma unroll
            for (int n = 0; n < 4; ++n) {
                int br = wc * 64 + n * 16 + lr;
                bv[n] = *(const short8*)(Bs + ((br * 128 + lkb) ^ ((br & 7) << 4)));
            }
#pragma unroll
            for (int m = 0; m < 2; ++m)
#pragma unroll
                for (int n = 0; n < 4; ++n)
                    acc[m][n] = __builtin_amdgcn_mfma_f32_16x16x32_bf16(av[m], bv[n], acc[m][n], 0, 0, 0);
        }
        __syncthreads();
    }
    int lr4 = (lane >> 4) * 4, lc = lane & 15;
#pragma unroll
    for (int m = 0; m < 2; ++m) {
        int gr = r0 + wr * 32 + m * 16 + lr4;
#pragma unroll
        for (int n = 0; n < 4; ++n) {
            int gc = wc * 64 + n * 16 + lc;
#pragma unroll
            for (int j = 0; j < 4; ++j)
                d[(size_t)(gr + j) * 128 + gc] = acc[m][n][j];
        }
    }
}

// ---------------- K4: sampling params ----------------
__global__ __launch_bounds__(256) void k_off(const float* __restrict__ d,
        const float* __restrict__ offb, const float* __restrict__ modb,
        const float* __restrict__ gate,
        int* __restrict__ idx0, int* __restrict__ idx1,
        float* __restrict__ w0a, float* __restrict__ w1a) {
    int flat = blockIdx.x * 256 + threadIdx.x;   // b*7*L + k*L + p
    if (flat >= NKP) return;
    int p = flat & (LL - 1);
    int k = (flat >> 12) % KHH;
    int b = flat / (KHH * LL);
    float offa = offb[k], moda = modb[k];
#pragma unroll
    for (int j = 0; j < KHH; ++j) {
        int q = p + j - PADK;
        if (q >= 0 && q < LL) {
            const float* dr = d + (size_t)(b * LL + q) * 128;
            offa += dr[k * 7 + j];
            moda += dr[49 + k * 7 + j];
        }
    }
    float modv = 2.f / (1.f + expf(-moda));
    float pos = (float)(p - PADK + k) + offa;
    pos = fminf(fmaxf(pos, -1.0e9f), 1.0e9f);
    float f = floorf(pos);
    float tf = pos - f;
    int i0 = (int)f;
    int i1 = i0 + 1;
    float in0 = (i0 >= 0 && i0 < LL) ? 1.f : 0.f;
    float in1 = (i1 >= 0 && i1 < LL) ? 1.f : 0.f;
    int c0 = min(max(i0, 0), LL - 1);
    int c1 = min(max(i1, 0), LL - 1);
    float g0 = gate[b * LL + c0] * in0;
    float g1 = gate[b * LL + c1] * in1;
    w0a[flat] = modv * (1.f - tf) * g0;
    w1a[flat] = modv * tf * g1;
    idx0[flat] = c0;
    idx1[flat] = c1;
}

// ---------------- K5: fused sample+GEMM; 8 waves x (128x48 strip), cvt_pk lerp, open scheduling ----------------
// BM=128, BN=384, BK=64; 512 threads = 8 waves (1x8), wave strip 128x48 = 8x3 frags 16x16x32

#define STEPOFF 49152   // 8 kc per step * 768 * 8 elems
#define KSOFF   24576   // 4 kc * 768 * 8 elems

#define LOADB3(Q, KS, D0, D1, D2) do { \
    const unsigned short* _q = (Q) + (KS) * KSOFF; \
    D0 = *(const short8*)(_q); \
    D1 = *(const short8*)(_q + 128); \
    D2 = *(const short8*)(_q + 256); \
} while (0)

#define MFMA_ROW3(AV, M, B0, B1, B2) \
    acc[M][0] = __builtin_amdgcn_mfma_f32_16x16x32_bf16(AV, B0, acc[M][0], 0, 0, 0); \
    acc[M][1] = __builtin_amdgcn_mfma_f32_16x16x32_bf16(AV, B1, acc[M][1], 0, 0, 0); \
    acc[M][2] = __builtin_amdgcn_mfma_f32_16x16x32_bf16(AV, B2, acc[M][2], 0, 0, 0);

#define COMPUTE_KS3(ASB, KS, B0, B1, B2) do { \
    __builtin_amdgcn_s_setprio(1); \
    int _lkb = ke0 * 2 + (KS) * 64; \
    short8 _av0, _av1, _av2, _av3, _av4, _av5, _av6, _av7; \
    { int ar = 0 * 16 + lr; _av0 = *(const short8*)((ASB) + ar * 128 + (_lkb ^ ((ar & 7) << 4))); } \
    { int ar = 1 * 16 + lr; _av1 = *(const short8*)((ASB) + ar * 128 + (_lkb ^ ((ar & 7) << 4))); } \
    { int ar = 2 * 16 + lr; _av2 = *(const short8*)((ASB) + ar * 128 + (_lkb ^ ((ar & 7) << 4))); } \
    { int ar = 3 * 16 + lr; _av3 = *(const short8*)((ASB) + ar * 128 + (_lkb ^ ((ar & 7) << 4))); } \
    MFMA_ROW3(_av0, 0, B0, B1, B2) \
    MFMA_ROW3(_av1, 1, B0, B1, B2) \
    MFMA_ROW3(_av2, 2, B0, B1, B2) \
    MFMA_ROW3(_av3, 3, B0, B1, B2) \
    { int ar = 4 * 16 + lr; _av4 = *(const short8*)((ASB) + ar * 128 + (_lkb ^ ((ar & 7) << 4))); } \
    { int ar = 5 * 16 + lr; _av5 = *(const short8*)((ASB) + ar * 128 + (_lkb ^ ((ar & 7) << 4))); } \
    { int ar = 6 * 16 + lr; _av6 = *(const short8*)((ASB) + ar * 128 + (_lkb ^ ((ar & 7) << 4))); } \
    { int ar = 7 * 16 + lr; _av7 = *(const short8*)((ASB) + ar * 128 + (_lkb ^ ((ar & 7) << 4))); } \
    MFMA_ROW3(_av4, 4, B0, B1, B2) \
    MFMA_ROW3(_av5, 5, B0, B1, B2) \
    MFMA_ROW3(_av6, 6, B0, B1, B2) \
    MFMA_ROW3(_av7, 7, B0, B1, B2) \
    __builtin_amdgcn_s_setprio(0); \
} while (0)

// counted barrier (T4): LDS drained, global loads stay in flight across the barrier
#define BAR() do { \
    asm volatile("s_waitcnt lgkmcnt(0)" ::: "memory"); \
    __builtin_amdgcn_s_barrier(); \
    __builtin_amdgcn_sched_barrier(0); \
} while (0)

__global__ __launch_bounds__(512, 2) void k_fgemm(const unsigned short* __restrict__ hb,
        const unsigned short* __restrict__ Wbt,
        const int* __restrict__ idx0, const int* __restrict__ idx1,
        const float* __restrict__ w0a, const float* __restrict__ w1a,
        const float* __restrict__ resid, float* __restrict__ out) {
    __shared__ __align__(16) char As[2][128 * 128];

    int bid = blockIdx.x;
    int nhalf = (bid & 7) >> 2;                 // XCDs 0-3 -> half 0, 4-7 -> half 1
    int rowtile = (bid >> 3) * 4 + (bid & 3);   // bijective 0..127
    int r0 = rowtile * 128;
    int o0 = nhalf * 384;
    int b = r0 >> 12;
    int p0 = r0 & (LL - 1);
    int pbase = ((b * KHH) << 12) + p0;
    const unsigned short* hbB = hb + (size_t)b * LL * CC;

    int t = threadIdx.x;
    int lane = t & 63, wc = t >> 6;             // wave 0..7 owns 48-col strip
    int lr = lane & 15;
    int ke0 = (lane >> 4) * 8;     // elem offset of lane's 8-elem k-chunk

    // per-lane B base pointer into Wbt; advances STEPOFF per step
    const unsigned short* pB = Wbt + ((size_t)(lane >> 4) * CC + o0 + wc * 48 + lr) * 8;

    // A-build mapping: row = t>>2 (0..127), seg = t&3 (16 elems each)
    int arow = t >> 2, aseg = t & 3;
    int acolb = aseg * 32;
    int aswz0 = arow * 128 + (acolb ^ ((arow & 7) << 4));
    int aswz1 = arow * 128 + ((acolb + 16) ^ ((arow & 7) << 4));

    f32x4 acc[8][3];
#pragma unroll
    for (int m = 0; m < 8; ++m)
#pragma unroll
        for (int n = 0; n < 3; ++n) acc[m][n] = (f32x4){0.f, 0.f, 0.f, 0.f};

    // per-tap sampling regs + incremental gather pointers
    float wa = 0.f, wbv = 0.f;
    int cur_tap = -1;
    const unsigned short* pA0 = hbB;
    const unsigned short* pA1 = hbB;

    // staging registers (all individually named)
    ushort8 la0, la1, la2, la3;
    short8 S0_0, S0_1, S0_2;   // ks0 buffer (even steps)
    short8 S1_0, S1_1, S1_2;   // ks1 buffer (reloaded late every step)
    short8 S2_0, S2_1, S2_2;   // ks0 buffer (odd steps)

    auto loadA = [&](int tap, int c0) {
        if (tap != cur_tap) {
            int pf = pbase + (tap << 12) + arow;
            int g0 = idx0[pf], g1 = idx1[pf];
            wa = w0a[pf];  wbv = w1a[pf];
            cur_tap = tap;
            pA0 = hbB + (size_t)g0 * CC + c0 + aseg * 16;
            pA1 = hbB + (size_t)g1 * CC + c0 + aseg * 16;
        } else {
            pA0 += 64;
            pA1 += 64;
        }
        la0 = *(const ushort8*)(pA0);
        la1 = *(const ushort8*)(pA0 + 8);
        la2 = *(const ushort8*)(pA1);
        la3 = *(const ushort8*)(pA1 + 8);
    };

    auto writeA = [&](char* Asb) {
        uint4v va, vb;
#pragma unroll
        for (int p = 0; p < 4; ++p) {
            float lo = fmaf(wa, bf2f(la0[2 * p]),     wbv * bf2f(la2[2 * p]));
            float hi = fmaf(wa, bf2f(la0[2 * p + 1]), wbv * bf2f(la2[2 * p + 1]));
            va[p] = cvtpk(lo, hi);
        }
#pragma unroll
        for (int p = 0; p < 4; ++p) {
            float lo = fmaf(wa, bf2f(la1[2 * p]),     wbv * bf2f(la3[2 * p]));
            float hi = fmaf(wa, bf2f(la1[2 * p + 1]), wbv * bf2f(la3[2 * p + 1]));
            vb[p] = cvtpk(lo, hi);
        }
        *(uint4v*)(Asb + aswz0) = va;
        *(uint4v*)(Asb + aswz1) = vb;
    };

    // prologue: step 0 fully staged
    loadA(0, 0);
    LOADB3(pB, 0, S0_0, S0_1, S0_2);
    LOADB3(pB, 1, S1_0, S1_1, S1_2);
    writeA(As[0]);
    BAR();

    int tap_c = 0, c0_c = 0;
    for (int sp = 0; sp < NT; sp += 2) {
        // ---------------- even step s = sp (computes As[0], S0/S1) ----------------
        {
            int tap_n = tap_c, c0_n = c0_c + 64;
            if (c0_n == CC) { c0_n = 0; ++tap_n; }
            bool more = (sp + 1 < NT);
            const unsigned short* pN = pB + STEPOFF;
            if (more) {
                LOADB3(pN, 0, S2_0, S2_1, S2_2);
                loadA(tap_n, c0_n);
            }
            __builtin_amdgcn_sched_barrier(0);
            COMPUTE_KS3(As[0], 0, S0_0, S0_1, S0_2);
            COMPUTE_KS3(As[0], 1, S1_0, S1_1, S1_2);
            if (more) {
                LOADB3(pN, 1, S1_0, S1_1, S1_2);
                writeA(As[1]);
            }
            BAR();
            pB = pN;
            tap_c = tap_n; c0_c = c0_n;
        }
        // ---------------- odd step s = sp+1 (computes As[1], S2/S1) ----------------
        {
            int s = sp + 1;
            if (s >= NT) break;
            int tap_n = tap_c, c0_n = c0_c + 64;
            if (c0_n == CC) { c0_n = 0; ++tap_n; }
            bool more = (s + 1 < NT);
            const unsigned short* pN = pB + STEPOFF;
            if (more) {
                LOADB3(pN, 0, S0_0, S0_1, S0_2);
                loadA(tap_n, c0_n);
            }
            __builtin_amdgcn_sched_barrier(0);
            COMPUTE_KS3(As[1], 0, S2_0, S2_1, S2_2);
            COMPUTE_KS3(As[1], 1, S1_0, S1_1, S1_2);
            if (more) {
                LOADB3(pN, 1, S1_0, S1_1, S1_2);
                writeA(As[0]);
            }
            BAR();
            pB = pN;
            tap_c = tap_n; c0_c = c0_n;
        }
    }

    // epilogue: + residual
    int lr4 = (lane >> 4) * 4, lc = lane & 15;
#pragma unroll
    for (int m = 0; m < 8; ++m) {
        int gr = r0 + m * 16 + lr4;
#pragma unroll
        for (int n = 0; n < 3; ++n) {
            int gc = o0 + wc * 48 + n * 16 + lc;
#pragma unroll
            for (int j = 0; j < 4; ++j) {
                size_t idx = (size_t)(gr + j) * CC + gc;
                out[idx] = acc[m][n][j] + resid[idx];
            }
        }
    }
}

extern "C" void kernel_launch(void* const* d_in, const int* in_sizes, int n_in,
                              void* d_out, int out_size, void* d_ws, size_t ws_size,
                              hipStream_t stream) {
    const float* x   = (const float*)d_in[0];
    const float* am  = (const float*)d_in[1];
    const float* stm = (const float*)d_in[2];
    const float* lnw = (const float*)d_in[3];
    const float* lnb = (const float*)d_in[4];
    const float* ow  = (const float*)d_in[5];
    const float* ob  = (const float*)d_in[6];
    const float* mw  = (const float*)d_in[7];
    const float* mb  = (const float*)d_in[8];
    const float* rw  = (const float*)d_in[9];
    float* out = (float*)d_out;

    char* ws = (char*)d_ws;
    size_t off = 0;
    auto carve = [&](size_t bytes) -> char* {
        char* p = ws + off;
        off += (bytes + 255) & ~(size_t)255;
        return p;
    };
    unsigned short* hb  = (unsigned short*)carve((size_t)ROWS * CC * 2);   // 25.2 MB
    unsigned short* wbt = (unsigned short*)carve((size_t)NKC * CC * 8 * 2);// 8.25 MB
    unsigned short* wcb = (unsigned short*)carve((size_t)128 * CC * 2);    // 0.20 MB
    float* d    = (float*)carve((size_t)ROWS * 128 * 4);                   // 8.4 MB
    float* gate = (float*)carve((size_t)ROWS * 4);
    int*   i0   = (int*)carve((size_t)NKP * 4);
    int*   i1   = (int*)carve((size_t)NKP * 4);
    float* w0   = (float*)carve((size_t)NKP * 4);
    float* w1   = (float*)carve((size_t)NKP * 4);

    k_ln<<<ROWS, 64, 0, stream>>>(x, am, stm, lnw, lnb, hb, gate);
    k_wbt<<<CC / 4, 256, 0, stream>>>(rw, wbt);
    k_wcb<<<128, 256, 0, stream>>>(ow, mw, wcb);
    k_dg2<<<ROWS / 64, 256, 0, stream>>>(hb, wcb, d);
    k_off<<<NKP / 256, 256, 0, stream>>>(d, ob, mb, gate, i0, i1, w0, w1);
    k_fgemm<<<256, 512, 0, stream>>>(hb, wbt, i0, i1, w0, w1, x, out);
}